// Round 1
// baseline (652.588 us; speedup 1.0000x reference)
//
#include <hip/hip_runtime.h>
#include <hip/hip_bf16.h>

// GCN encoder: h = emb[x]; repeat 4x { hw = h@W; h = scatter_add(hw[src]*norm -> dst) + bias }; out = h[ptr[1:]-1]
// Strategy: build CSR-by-dst once (atomic-free aggregation), LDS-tiled f32 GEMM (no fp32 MFMA on CDNA4).

#define D 128
#define GR 32  // GEMM rows per block

// ---- degree histogram over dst ----
__global__ void hist_kernel(const int* __restrict__ dst, int* __restrict__ deg, int E) {
    int e = blockIdx.x * blockDim.x + threadIdx.x;
    if (e < E) atomicAdd(&deg[dst[e]], 1);
}

// ---- deg_inv_sqrt ----
__global__ void dis_kernel(const int* __restrict__ deg, float* __restrict__ dis, int n) {
    int i = blockIdx.x * blockDim.x + threadIdx.x;
    if (i < n) {
        int d = deg[i];
        dis[i] = (d > 0) ? rsqrtf((float)d) : 0.0f;
    }
}

// ---- single-block exclusive scan: row_ptr[0..n] from deg[0..n-1] ----
__global__ void scan_kernel(const int* __restrict__ deg, int* __restrict__ row_ptr, int n) {
    __shared__ int buf[1024];
    __shared__ int carry;
    int tid = threadIdx.x;
    if (tid == 0) { carry = 0; row_ptr[0] = 0; }
    __syncthreads();
    for (int base = 0; base < n; base += 1024) {
        int i = base + tid;
        int v = (i < n) ? deg[i] : 0;
        buf[tid] = v;
        __syncthreads();
        // Hillis-Steele inclusive scan
        for (int off = 1; off < 1024; off <<= 1) {
            int t = (tid >= off) ? buf[tid - off] : 0;
            __syncthreads();
            buf[tid] += t;
            __syncthreads();
        }
        if (i < n) row_ptr[i + 1] = carry + buf[tid];
        __syncthreads();
        if (tid == 0) carry += buf[1023];
        __syncthreads();
    }
}

// ---- scatter edges into CSR (by dst); edge norm = dis[src]*dis[dst] ----
__global__ void fill_csr_kernel(const int* __restrict__ src, const int* __restrict__ dst,
                                const float* __restrict__ dis, const int* __restrict__ row_ptr,
                                int* __restrict__ cnt, int* __restrict__ col_idx,
                                float* __restrict__ enorm, int E) {
    int e = blockIdx.x * blockDim.x + threadIdx.x;
    if (e >= E) return;
    int s = src[e], d = dst[e];
    int pos = row_ptr[d] + atomicAdd(&cnt[d], 1);
    col_idx[pos] = s;
    enorm[pos] = dis[s] * dis[d];
}

// ---- embedding gather: h[i] = emb[x[i]] (float4 per thread) ----
__global__ void embed_kernel(const int* __restrict__ x, const float* __restrict__ emb,
                             float* __restrict__ h, int n) {
    int t = blockIdx.x * blockDim.x + threadIdx.x;
    if (t >= n * (D / 4)) return;
    int i = t >> 5, c4 = t & 31;              // D/4 = 32 float4 per row
    int tok = x[i];
    ((float4*)h)[(size_t)i * 32 + c4] = ((const float4*)emb)[(size_t)tok * 32 + c4];
}

// ---- hw = h @ W : W (64KB) + 32-row h tile (16KB) in LDS; 4x4 register block ----
__global__ __launch_bounds__(256) void gemm_kernel(const float* __restrict__ h,
                                                   const float* __restrict__ W,
                                                   float* __restrict__ hw, int n) {
    __shared__ float wl[D * D];     // 64 KB
    __shared__ float hl[GR * D];    // 16 KB
    int tid = threadIdx.x;
    const float4* W4 = (const float4*)W;
    float4* wl4 = (float4*)wl;
    for (int i = tid; i < D * D / 4; i += 256) wl4[i] = W4[i];
    int row0 = blockIdx.x * GR;
    const float4* h4 = (const float4*)h;
    float4* hl4 = (float4*)hl;
    for (int i = tid; i < GR * (D / 4); i += 256) {
        int row = row0 + (i >> 5);
        float4 z = {0.f, 0.f, 0.f, 0.f};
        hl4[i] = (row < n) ? h4[(size_t)row0 * 32 + i] : z;
    }
    __syncthreads();
    int r0 = (tid >> 5) * 4;        // 0..28 (4 rows)
    int c0 = (tid & 31) * 4;        // 0..124 (4 cols)
    float4 acc0 = {0,0,0,0}, acc1 = {0,0,0,0}, acc2 = {0,0,0,0}, acc3 = {0,0,0,0};
    #pragma unroll 8
    for (int k = 0; k < D; k++) {
        float4 w = *(const float4*)&wl[k * D + c0];
        float a0 = hl[(r0 + 0) * D + k];
        float a1 = hl[(r0 + 1) * D + k];
        float a2 = hl[(r0 + 2) * D + k];
        float a3 = hl[(r0 + 3) * D + k];
        acc0.x += a0 * w.x; acc0.y += a0 * w.y; acc0.z += a0 * w.z; acc0.w += a0 * w.w;
        acc1.x += a1 * w.x; acc1.y += a1 * w.y; acc1.z += a1 * w.z; acc1.w += a1 * w.w;
        acc2.x += a2 * w.x; acc2.y += a2 * w.y; acc2.z += a2 * w.z; acc2.w += a2 * w.w;
        acc3.x += a3 * w.x; acc3.y += a3 * w.y; acc3.z += a3 * w.z; acc3.w += a3 * w.w;
    }
    float4 accs[4] = {acc0, acc1, acc2, acc3};
    #pragma unroll
    for (int r = 0; r < 4; r++) {
        int row = row0 + r0 + r;
        if (row < n) *(float4*)&hw[(size_t)row * D + c0] = accs[r];
    }
}

// ---- h_out[i] = sum_{e in CSR row i} hw[col[e]] * enorm[e] + bias : one wave per node ----
__global__ __launch_bounds__(256) void agg_kernel(const float* __restrict__ hw,
                                                  const int* __restrict__ row_ptr,
                                                  const int* __restrict__ col_idx,
                                                  const float* __restrict__ enorm,
                                                  const float* __restrict__ bias,
                                                  float* __restrict__ hout, int n) {
    int node = (blockIdx.x * blockDim.x + threadIdx.x) >> 6;
    int lane = threadIdx.x & 63;
    if (node >= n) return;
    int beg = row_ptr[node], end = row_ptr[node + 1];
    float acc0 = 0.f, acc1 = 0.f;
    for (int j = beg; j < end; j++) {
        int s = col_idx[j];
        float w = enorm[j];
        acc0 += hw[(size_t)s * D + lane] * w;
        acc1 += hw[(size_t)s * D + 64 + lane] * w;
    }
    hout[(size_t)node * D + lane]      = acc0 + bias[lane];
    hout[(size_t)node * D + 64 + lane] = acc1 + bias[64 + lane];
}

// ---- out[b] = h[ptr[b+1]-1]; auto-detect int32 vs int64 ptr ----
__global__ void out_kernel(const int* __restrict__ ptr32, const float* __restrict__ h,
                           float* __restrict__ out, int B) {
    int t = blockIdx.x * blockDim.x + threadIdx.x;
    if (t >= B * 32) return;
    int b = t >> 5, c4 = t & 31;
    // int64 layout (LE): [v0,0,v1,0,...] -> ptr32[3] == 0 (hi word of ptr[1]); int32: ptr32[3] = ptr[3] > 0
    bool is64 = (ptr32[3] == 0);
    long long node;
    if (is64) node = ((const long long*)ptr32)[b + 1] - 1;
    else      node = (long long)ptr32[b + 1] - 1;
    ((float4*)out)[b * 32 + c4] = ((const float4*)h)[node * 32 + c4];
}

extern "C" void kernel_launch(void* const* d_in, const int* in_sizes, int n_in,
                              void* d_out, int out_size, void* d_ws, size_t ws_size,
                              hipStream_t stream) {
    const int*   x    = (const int*)d_in[0];
    const int*   ei   = (const int*)d_in[1];
    const int*   ptr  = (const int*)d_in[2];   // width auto-detected on device
    const float* emb  = (const float*)d_in[4];
    const float* W    = (const float*)d_in[5];
    const float* bias = (const float*)d_in[6];

    const int N = in_sizes[0];
    const int E = in_sizes[1] / 2;
    const int B = in_sizes[2] - 1;
    const int DEPTH = 4;                        // fixed by problem; device scalar unreadable during capture

    const int* src = ei;
    const int* dst = ei + E;

    // workspace carve-up (256B aligned)
    char* ws = (char*)d_ws;
    size_t off = 0;
    auto carve = [&](size_t bytes) -> void* {
        void* p = ws + off;
        off += (bytes + 255) & ~(size_t)255;
        return p;
    };
    float* h       = (float*)carve((size_t)N * D * 4);
    float* hw      = (float*)carve((size_t)N * D * 4);
    int*   deg     = (int*)  carve((size_t)N * 4);
    float* dis     = (float*)carve((size_t)N * 4);
    int*   row_ptr = (int*)  carve((size_t)(N + 1) * 4);
    int*   cnt     = (int*)  carve((size_t)N * 4);
    int*   col_idx = (int*)  carve((size_t)E * 4);
    float* enorm   = (float*)carve((size_t)E * 4);

    hipMemsetAsync(deg, 0, (size_t)N * 4, stream);
    hipMemsetAsync(cnt, 0, (size_t)N * 4, stream);

    hist_kernel<<<(E + 255) / 256, 256, 0, stream>>>(dst, deg, E);
    dis_kernel<<<(N + 255) / 256, 256, 0, stream>>>(deg, dis, N);
    scan_kernel<<<1, 1024, 0, stream>>>(deg, row_ptr, N);
    fill_csr_kernel<<<(E + 255) / 256, 256, 0, stream>>>(src, dst, dis, row_ptr, cnt,
                                                         col_idx, enorm, E);
    embed_kernel<<<((size_t)N * 32 + 255) / 256, 256, 0, stream>>>(x, emb, h, N);

    for (int l = 0; l < DEPTH; l++) {
        gemm_kernel<<<(N + GR - 1) / GR, 256, 0, stream>>>(h, W, hw, N);
        agg_kernel<<<((size_t)N * 64 + 255) / 256, 256, 0, stream>>>(hw, row_ptr, col_idx,
                                                                     enorm, bias, h, N);
    }
    out_kernel<<<(B * 32 + 255) / 256, 256, 0, stream>>>(ptr, h, (float*)d_out, B);
}

// Round 3
// 584.338 us; speedup vs baseline: 1.1168x; 1.1168x over previous
//
#include <hip/hip_runtime.h>
#include <hip/hip_bf16.h>

// GCN encoder: h = emb[x]; repeat 4x { hw = h@W; h = scatter_add(hw[src]*norm -> dst) + bias }; out = h[ptr[1:]-1]
// CSR-by-dst build (atomic-free aggregation), LDS-tiled f32 GEMM (no fp32 MFMA on CDNA4).
// R2 (resubmit, infra timeout): multi-block scan (was 87us single-block, 0.18% occupancy);
// agg inner loop float2 (1 ld/edge/lane).

#define D 128
#define GR 32  // GEMM rows per block

// ---- degree histogram over dst ----
__global__ void hist_kernel(const int* __restrict__ dst, int* __restrict__ deg, int E) {
    int e = blockIdx.x * blockDim.x + threadIdx.x;
    if (e < E) atomicAdd(&deg[dst[e]], 1);
}

// ---- deg_inv_sqrt ----
__global__ void dis_kernel(const int* __restrict__ deg, float* __restrict__ dis, int n) {
    int i = blockIdx.x * blockDim.x + threadIdx.x;
    if (i < n) {
        int d = deg[i];
        dis[i] = (d > 0) ? rsqrtf((float)d) : 0.0f;
    }
}

__device__ __forceinline__ int wave_incl_scan(int v, int lane) {
    #pragma unroll
    for (int off = 1; off < 64; off <<= 1) {
        int t = __shfl_up(v, off);
        if (lane >= off) v += t;
    }
    return v;
}

// ---- scan stage A: bsum[b] = sum of deg[b*1024 .. b*1024+1023] ----
__global__ __launch_bounds__(256) void scan_reduce(const int* __restrict__ deg,
                                                   int* __restrict__ bsum, int n) {
    __shared__ int wsum[4];
    int b = blockIdx.x, tid = threadIdx.x;
    int s = 0;
    for (int j = tid; j < 1024; j += 256) {
        int idx = b * 1024 + j;
        if (idx < n) s += deg[idx];
    }
    #pragma unroll
    for (int off = 32; off; off >>= 1) s += __shfl_down(s, off);
    int lane = tid & 63, wid = tid >> 6;
    if (lane == 0) wsum[wid] = s;
    __syncthreads();
    if (tid == 0) bsum[b] = wsum[0] + wsum[1] + wsum[2] + wsum[3];
}

// ---- scan stage B: boff = exclusive scan of bsum (nb <= 1024, tiny) ----
__global__ void scan_bsum(const int* __restrict__ bsum, int* __restrict__ boff, int nb) {
    __shared__ int buf[1024];
    int tid = threadIdx.x;
    int v = (tid < nb) ? bsum[tid] : 0;
    buf[tid] = v;
    __syncthreads();
    for (int off = 1; off < 1024; off <<= 1) {
        int t = (tid >= off) ? buf[tid - off] : 0;
        __syncthreads();
        buf[tid] += t;
        __syncthreads();
    }
    if (tid < nb) boff[tid] = buf[tid] - v;
}

// ---- scan stage C: row_ptr[i+1] = boff[b] + inclusive local scan ----
__global__ __launch_bounds__(256) void scan_final(const int* __restrict__ deg,
                                                  const int* __restrict__ boff,
                                                  int* __restrict__ row_ptr, int n) {
    __shared__ int wsum[4];
    int b = blockIdx.x, tid = threadIdx.x;
    int lane = tid & 63, wid = tid >> 6;
    int base = b * 1024 + tid * 4;
    int v[4], s = 0;
    #pragma unroll
    for (int j = 0; j < 4; j++) {
        int idx = base + j;
        v[j] = (idx < n) ? deg[idx] : 0;
        s += v[j];
    }
    int incl = wave_incl_scan(s, lane);
    if (lane == 63) wsum[wid] = incl;
    __syncthreads();
    int woff = 0;
    for (int w = 0; w < wid; w++) woff += wsum[w];
    int run = incl - s + woff + boff[b];
    #pragma unroll
    for (int j = 0; j < 4; j++) {
        int idx = base + j;
        run += v[j];
        if (idx < n) row_ptr[idx + 1] = run;
    }
    if (b == 0 && tid == 0) row_ptr[0] = 0;
}

// ---- scatter edges into CSR (by dst); edge norm = dis[src]*dis[dst] ----
__global__ void fill_csr_kernel(const int* __restrict__ src, const int* __restrict__ dst,
                                const float* __restrict__ dis, const int* __restrict__ row_ptr,
                                int* __restrict__ cnt, int* __restrict__ col_idx,
                                float* __restrict__ enorm, int E) {
    int e = blockIdx.x * blockDim.x + threadIdx.x;
    if (e >= E) return;
    int s = src[e], d = dst[e];
    int pos = row_ptr[d] + atomicAdd(&cnt[d], 1);
    col_idx[pos] = s;
    enorm[pos] = dis[s] * dis[d];
}

// ---- embedding gather: h[i] = emb[x[i]] (float4 per thread) ----
__global__ void embed_kernel(const int* __restrict__ x, const float* __restrict__ emb,
                             float* __restrict__ h, int n) {
    int t = blockIdx.x * blockDim.x + threadIdx.x;
    if (t >= n * (D / 4)) return;
    int i = t >> 5, c4 = t & 31;              // D/4 = 32 float4 per row
    int tok = x[i];
    ((float4*)h)[(size_t)i * 32 + c4] = ((const float4*)emb)[(size_t)tok * 32 + c4];
}

// ---- hw = h @ W : W (64KB) + 32-row h tile (16KB) in LDS; 4x4 register block ----
__global__ __launch_bounds__(256) void gemm_kernel(const float* __restrict__ h,
                                                   const float* __restrict__ W,
                                                   float* __restrict__ hw, int n) {
    __shared__ float wl[D * D];     // 64 KB
    __shared__ float hl[GR * D];    // 16 KB
    int tid = threadIdx.x;
    const float4* W4 = (const float4*)W;
    float4* wl4 = (float4*)wl;
    for (int i = tid; i < D * D / 4; i += 256) wl4[i] = W4[i];
    int row0 = blockIdx.x * GR;
    const float4* h4 = (const float4*)h;
    float4* hl4 = (float4*)hl;
    for (int i = tid; i < GR * (D / 4); i += 256) {
        int row = row0 + (i >> 5);
        float4 z = {0.f, 0.f, 0.f, 0.f};
        hl4[i] = (row < n) ? h4[(size_t)row0 * 32 + i] : z;
    }
    __syncthreads();
    int r0 = (tid >> 5) * 4;        // 0..28 (4 rows)
    int c0 = (tid & 31) * 4;        // 0..124 (4 cols)
    float4 acc0 = {0,0,0,0}, acc1 = {0,0,0,0}, acc2 = {0,0,0,0}, acc3 = {0,0,0,0};
    #pragma unroll 8
    for (int k = 0; k < D; k++) {
        float4 w = *(const float4*)&wl[k * D + c0];
        float a0 = hl[(r0 + 0) * D + k];
        float a1 = hl[(r0 + 1) * D + k];
        float a2 = hl[(r0 + 2) * D + k];
        float a3 = hl[(r0 + 3) * D + k];
        acc0.x += a0 * w.x; acc0.y += a0 * w.y; acc0.z += a0 * w.z; acc0.w += a0 * w.w;
        acc1.x += a1 * w.x; acc1.y += a1 * w.y; acc1.z += a1 * w.z; acc1.w += a1 * w.w;
        acc2.x += a2 * w.x; acc2.y += a2 * w.y; acc2.z += a2 * w.z; acc2.w += a2 * w.w;
        acc3.x += a3 * w.x; acc3.y += a3 * w.y; acc3.z += a3 * w.z; acc3.w += a3 * w.w;
    }
    float4 accs[4] = {acc0, acc1, acc2, acc3};
    #pragma unroll
    for (int r = 0; r < 4; r++) {
        int row = row0 + r0 + r;
        if (row < n) *(float4*)&hw[(size_t)row * D + c0] = accs[r];
    }
}

// ---- h_out[i] = sum_{e in row i} hw[col[e]] * enorm[e] + bias : one wave/node, float2/lane ----
__global__ __launch_bounds__(256) void agg_kernel(const float* __restrict__ hw,
                                                  const int* __restrict__ row_ptr,
                                                  const int* __restrict__ col_idx,
                                                  const float* __restrict__ enorm,
                                                  const float* __restrict__ bias,
                                                  float* __restrict__ hout, int n) {
    int node = (blockIdx.x * blockDim.x + threadIdx.x) >> 6;
    int lane = threadIdx.x & 63;
    if (node >= n) return;
    int beg = row_ptr[node], end = row_ptr[node + 1];
    const float2* hw2 = (const float2*)hw;
    float ax = 0.f, ay = 0.f;
    for (int j = beg; j < end; j++) {
        int s = col_idx[j];
        float w = enorm[j];
        float2 v = hw2[(size_t)s * 64 + lane];
        ax += v.x * w; ay += v.y * w;
    }
    float2 bb = ((const float2*)bias)[lane];
    float2 r; r.x = ax + bb.x; r.y = ay + bb.y;
    ((float2*)hout)[(size_t)node * 64 + lane] = r;
}

// ---- out[b] = h[ptr[b+1]-1]; auto-detect int32 vs int64 ptr ----
__global__ void out_kernel(const int* __restrict__ ptr32, const float* __restrict__ h,
                           float* __restrict__ out, int B) {
    int t = blockIdx.x * blockDim.x + threadIdx.x;
    if (t >= B * 32) return;
    int b = t >> 5, c4 = t & 31;
    bool is64 = (ptr32[3] == 0);   // hi word of ptr[1] is 0 iff int64 (ptr values > 0)
    long long node;
    if (is64) node = ((const long long*)ptr32)[b + 1] - 1;
    else      node = (long long)ptr32[b + 1] - 1;
    ((float4*)out)[b * 32 + c4] = ((const float4*)h)[node * 32 + c4];
}

extern "C" void kernel_launch(void* const* d_in, const int* in_sizes, int n_in,
                              void* d_out, int out_size, void* d_ws, size_t ws_size,
                              hipStream_t stream) {
    const int*   x    = (const int*)d_in[0];
    const int*   ei   = (const int*)d_in[1];
    const int*   ptr  = (const int*)d_in[2];   // width auto-detected on device
    const float* emb  = (const float*)d_in[4];
    const float* W    = (const float*)d_in[5];
    const float* bias = (const float*)d_in[6];

    const int N = in_sizes[0];
    const int E = in_sizes[1] / 2;
    const int B = in_sizes[2] - 1;
    const int DEPTH = 4;                        // fixed by problem; device scalar unreadable during capture

    const int* src = ei;
    const int* dst = ei + E;

    // workspace carve-up (256B aligned)
    char* ws = (char*)d_ws;
    size_t off = 0;
    auto carve = [&](size_t bytes) -> void* {
        void* p = ws + off;
        off += (bytes + 255) & ~(size_t)255;
        return p;
    };
    float* h       = (float*)carve((size_t)N * D * 4);
    float* hw      = (float*)carve((size_t)N * D * 4);
    int*   deg     = (int*)  carve((size_t)N * 4);
    float* dis     = (float*)carve((size_t)N * 4);
    int*   row_ptr = (int*)  carve((size_t)(N + 1) * 4);
    int*   cnt     = (int*)  carve((size_t)N * 4);
    int*   col_idx = (int*)  carve((size_t)E * 4);
    float* enorm   = (float*)carve((size_t)E * 4);
    int    nb      = (N + 1023) / 1024;
    int*   bsum    = (int*)  carve((size_t)nb * 4);
    int*   boff    = (int*)  carve((size_t)nb * 4);

    hipMemsetAsync(deg, 0, (size_t)N * 4, stream);
    hipMemsetAsync(cnt, 0, (size_t)N * 4, stream);

    hist_kernel<<<(E + 255) / 256, 256, 0, stream>>>(dst, deg, E);
    dis_kernel<<<(N + 255) / 256, 256, 0, stream>>>(deg, dis, N);
    scan_reduce<<<nb, 256, 0, stream>>>(deg, bsum, N);
    scan_bsum<<<1, 1024, 0, stream>>>(bsum, boff, nb);
    scan_final<<<nb, 256, 0, stream>>>(deg, boff, row_ptr, N);
    fill_csr_kernel<<<(E + 255) / 256, 256, 0, stream>>>(src, dst, dis, row_ptr, cnt,
                                                         col_idx, enorm, E);
    embed_kernel<<<((size_t)N * 32 + 255) / 256, 256, 0, stream>>>(x, emb, h, N);

    for (int l = 0; l < DEPTH; l++) {
        gemm_kernel<<<(N + GR - 1) / GR, 256, 0, stream>>>(h, W, hw, N);
        agg_kernel<<<((size_t)N * 64 + 255) / 256, 256, 0, stream>>>(hw, row_ptr, col_idx,
                                                                     enorm, bias, h, N);
    }
    out_kernel<<<(B * 32 + 255) / 256, 256, 0, stream>>>(ptr, h, (float*)d_out, B);
}